// Round 6
// baseline (754.759 us; speedup 1.0000x reference)
//
#include <hip/hip_runtime.h>
#include <stdint.h>

#define NNODES 50000
#define NEDGES 800000
#define H 128
#define BN_EPS 1e-5f

typedef short short8 __attribute__((ext_vector_type(8)));
typedef float f32x4 __attribute__((ext_vector_type(4)));

__device__ __forceinline__ float bf2f(unsigned short u) {
    unsigned int v = ((unsigned int)u) << 16;
    return __uint_as_float(v);
}
__device__ __forceinline__ unsigned short f2bf(float f) {
    unsigned int x = __float_as_uint(f);
    return (unsigned short)((x + 0x7FFFu + ((x >> 16) & 1u)) >> 16);
}
__device__ __forceinline__ short8 s8z() { short8 z = {0,0,0,0,0,0,0,0}; return z; }

// ================= common MFMA tile core =================
template<int KB>
__device__ __forceinline__ void gemm_tile(const short* __restrict__ sA, const int SK,
                                          const unsigned short* __restrict__ WT, const int RK,
                                          const int n0, f32x4 acc[4][4], const int lane) {
    const int mr = lane & 15, quad = lane >> 4;
    const short* W = (const short*)WT;
    #pragma unroll
    for (int kb = 0; kb < KB; ++kb) {
        short8 a[4];
        #pragma unroll
        for (int mt = 0; mt < 4; ++mt)
            a[mt] = *(const short8*)&sA[(mt*16 + mr)*SK + kb*32 + quad*8];
        #pragma unroll
        for (int nt = 0; nt < 4; ++nt) {
            short8 b = *(const short8*)&W[(size_t)(n0 + nt*16 + mr)*RK + kb*32 + quad*8];
            #pragma unroll
            for (int mt = 0; mt < 4; ++mt)
                acc[mt][nt] = __builtin_amdgcn_mfma_f32_16x16x32_bf16(a[mt], b, acc[mt][nt], 0, 0, 0);
        }
    }
}

// ---- fold We2@Wm -> W2m (f32), b2m = be2@Wm + bm ----
__global__ void k_fold(const float* __restrict__ We2, const float* __restrict__ be2,
                       const float* __restrict__ Wm, const float* __restrict__ bm,
                       float* __restrict__ W2m, float* __restrict__ b2m) {
    int j = threadIdx.x;
    int i = blockIdx.x;
    if (i < H) {
        float acc = 0.f;
        for (int k = 0; k < H; ++k) acc = fmaf(We2[i*H + k], Wm[k*H + j], acc);
        W2m[i*H + j] = acc;
    } else {
        float acc = bm[j];
        for (int k = 0; k < H; ++k) acc = fmaf(be2[k], Wm[k*H + j], acc);
        b2m[j] = acc;
    }
}

// ---- transposed bf16 weight copies for MFMA B-frags ----
__global__ void k_prep2(const float* __restrict__ We1, const float* __restrict__ Wn1,
                        const float* __restrict__ Wn2, const float* __restrict__ W2m,
                        unsigned short* __restrict__ WabT, unsigned short* __restrict__ Wn1T,
                        unsigned short* __restrict__ Wn2T, unsigned short* __restrict__ W2mT,
                        unsigned short* __restrict__ WcT) {
    int i = blockIdx.x*256 + threadIdx.x;
    if (i < 16384) {                        // WabT[256][64]
        int n = i >> 6, k = i & 63;
        WabT[n*64 + k] = f2bf(We1[(n < 128 ? k : 64 + k)*H + (n & 127)]);
    } else if (i < 40960) {                 // Wn1T[128][192]
        int j = i - 16384; int n = j / 192, k = j - n*192;
        Wn1T[n*192 + k] = f2bf(Wn1[k*H + n]);
    } else if (i < 57344) {                 // Wn2T[128][128]
        int j = i - 40960; int n = j >> 7, k = j & 127;
        Wn2T[n*H + k] = f2bf(Wn2[k*H + n]);
    } else if (i < 73728) {                 // W2mT[128][128]
        int j = i - 57344; int n = j >> 7, k = j & 127;
        W2mT[n*H + k] = f2bf(W2m[k*H + n]);
    } else if (i < 77824) {                 // WcT[128][32], k>=16 zero (K padded for MFMA)
        int j = i - 73728; int n = j >> 5, k = j & 31;
        WcT[n*32 + k] = (k < 16) ? f2bf(We1[(128 + k)*H + n]) : (unsigned short)0;
    }
}

// ---- CSR build ----
__global__ void k_count(const int* __restrict__ ei, int* __restrict__ cnt) {
    int e = blockIdx.x*256 + threadIdx.x;
    if (e < NEDGES) atomicAdd(&cnt[ei[e]], 1);
}

__global__ void k_scan(const int* __restrict__ cnt, int* __restrict__ offsets,
                       int* __restrict__ cursor) {
    __shared__ int wsum[16];
    __shared__ int carry;
    const int tid = threadIdx.x;
    const int lane = tid & 63, wid = tid >> 6;
    if (tid == 0) carry = 0;
    for (int base = 0; base < NNODES; base += 1024) {
        int i = base + tid;
        int v = (i < NNODES) ? cnt[i] : 0;
        int xv = v;
        #pragma unroll
        for (int off = 1; off < 64; off <<= 1) {
            int y = __shfl_up(xv, off);
            if (lane >= off) xv += y;
        }
        if (lane == 63) wsum[wid] = xv;
        __syncthreads();
        if (tid == 0) {
            int a = carry;
            #pragma unroll
            for (int j = 0; j < 16; ++j) { int t = wsum[j]; wsum[j] = a; a += t; }
            carry = a;
        }
        __syncthreads();
        int excl = wsum[wid] + xv - v;
        if (i < NNODES) { offsets[i] = excl; cursor[i] = excl; }
        __syncthreads();
    }
    if (tid == 0) offsets[NNODES] = carry;
}

__global__ void k_scatter(const int* __restrict__ ei, int* __restrict__ cursor,
                          int* __restrict__ elist) {
    int e = blockIdx.x*256 + threadIdx.x;
    if (e < NEDGES) {
        int p = atomicAdd(&cursor[ei[e]], 1);
        elist[p] = e;
    }
}

// ---- T = x @ [Wa | Wb]  (bf16 out, [50000][256]) ----
__launch_bounds__(256)
__global__ void k_T(const float* __restrict__ x, const unsigned short* __restrict__ WabT,
                    unsigned short* __restrict__ T) {
    __shared__ short sA[128*72];
    const int tid = threadIdx.x;
    const int n0b = blockIdx.x*128;
    {
        const int rowl = tid >> 1, half = (tid & 1)*32;
        const int node = n0b + rowl;
        const bool ok = node < NNODES;
        #pragma unroll
        for (int c = 0; c < 4; ++c) {
            int k0 = half + c*8;
            short8 o = s8z();
            if (ok) {
                float4 a = *(const float4*)&x[node*64 + k0];
                float4 b = *(const float4*)&x[node*64 + k0 + 4];
                o[0]=(short)f2bf(a.x); o[1]=(short)f2bf(a.y); o[2]=(short)f2bf(a.z); o[3]=(short)f2bf(a.w);
                o[4]=(short)f2bf(b.x); o[5]=(short)f2bf(b.y); o[6]=(short)f2bf(b.z); o[7]=(short)f2bf(b.w);
            }
            *(short8*)&sA[rowl*72 + k0] = o;
        }
    }
    __syncthreads();
    const int wave = tid >> 6, lane = tid & 63;
    const int m0 = (wave & 1)*64;
    const int n0 = blockIdx.y*128 + (wave >> 1)*64;
    f32x4 acc[4][4];
    f32x4 z = {0.f, 0.f, 0.f, 0.f};
    #pragma unroll
    for (int mt = 0; mt < 4; ++mt)
        #pragma unroll
        for (int nt = 0; nt < 4; ++nt) acc[mt][nt] = z;
    gemm_tile<2>(sA + m0*72, 72, WabT, 64, n0, acc, lane);
    const int mr = lane & 15, quad = lane >> 4;
    #pragma unroll
    for (int nt = 0; nt < 4; ++nt) {
        int j = n0 + nt*16 + mr;
        #pragma unroll
        for (int mt = 0; mt < 4; ++mt) {
            int nb = n0b + m0 + mt*16 + quad*4;
            #pragma unroll
            for (int r = 0; r < 4; ++r) {
                int node = nb + r;
                if (node < NNODES) T[(size_t)node*256 + j] = f2bf(acc[mt][nt][r]);
            }
        }
    }
}

// ---- h1[p] (sorted order) = T1[row] + T2[col] + ea@Wc + be1 ; coalesced bf16 store ; BN stats ----
__launch_bounds__(256)
__global__ void k_gather2(const unsigned short* __restrict__ T, const int* __restrict__ ei,
                          const int* __restrict__ elist, const float* __restrict__ ea,
                          const unsigned short* __restrict__ WcT, const float* __restrict__ be1,
                          unsigned short* __restrict__ hb,
                          float* __restrict__ gS, float* __restrict__ gSS) {
    __shared__ short sEa[128*40];      // ea bf16, K=32 (upper 16 zero), pad to 40
    __shared__ short sT[128*136];      // bf16(T1+T2), later holds h1 tile for coalesced store
    __shared__ float sS[H], sSS[H];
    const int tid = threadIdx.x;
    if (tid < H) { sS[tid] = 0.f; sSS[tid] = 0.f; }
    const int p0 = blockIdx.x*128;
    const int lp = tid >> 1, half = tid & 1;
    const int e = elist[p0 + lp];
    const int row = ei[e], col = ei[NEDGES + e];
    {
        const float4* ea4 = (const float4*)ea;
        float4 a = ea4[e*4 + half*2];
        float4 b = ea4[e*4 + half*2 + 1];
        short8 o;
        o[0]=(short)f2bf(a.x); o[1]=(short)f2bf(a.y); o[2]=(short)f2bf(a.z); o[3]=(short)f2bf(a.w);
        o[4]=(short)f2bf(b.x); o[5]=(short)f2bf(b.y); o[6]=(short)f2bf(b.z); o[7]=(short)f2bf(b.w);
        *(short8*)&sEa[lp*40 + half*8] = o;
        *(short8*)&sEa[lp*40 + 16 + half*8] = s8z();
    }
    {
        #pragma unroll
        for (int c = 0; c < 8; ++c) {
            int jj = half*64 + c*8;
            short8 t1 = *(const short8*)&T[(size_t)row*256 + jj];
            short8 t2 = *(const short8*)&T[(size_t)col*256 + 128 + jj];
            short8 o;
            #pragma unroll
            for (int i = 0; i < 8; ++i)
                o[i] = (short)f2bf(bf2f((unsigned short)t1[i]) + bf2f((unsigned short)t2[i]));
            *(short8*)&sT[lp*136 + jj] = o;
        }
    }
    __syncthreads();
    const int wave = tid >> 6, lane = tid & 63;
    const int m0 = (wave & 1)*64, n0 = (wave >> 1)*64;
    f32x4 acc[4][4];
    f32x4 z = {0.f, 0.f, 0.f, 0.f};
    #pragma unroll
    for (int mt = 0; mt < 4; ++mt)
        #pragma unroll
        for (int nt = 0; nt < 4; ++nt) acc[mt][nt] = z;
    gemm_tile<1>(sEa + m0*40, 40, WcT, 32, n0, acc, lane);
    const int mr = lane & 15, quad = lane >> 4;
    // epilogue: h1 = acc + (T1+T2) + be1, write back into sT (each element owned by one lane)
    #pragma unroll
    for (int nt = 0; nt < 4; ++nt) {
        int j = n0 + nt*16 + mr;
        float bia = be1[j];
        float s = 0.f, ssum = 0.f;
        #pragma unroll
        for (int mt = 0; mt < 4; ++mt) {
            int m = m0 + mt*16 + quad*4;
            #pragma unroll
            for (int r = 0; r < 4; ++r) {
                float v = acc[mt][nt][r] + bf2f((unsigned short)sT[(m + r)*136 + j]) + bia;
                sT[(m + r)*136 + j] = (short)f2bf(v);
                s += v; ssum += v*v;
            }
        }
        atomicAdd(&sS[j], s);
        atomicAdd(&sSS[j], ssum);
    }
    __syncthreads();
    // coalesced 16B stores of the finished tile
    {
        const int hh = half*64;
        #pragma unroll
        for (int c = 0; c < 8; ++c)
            *(short8*)&hb[(size_t)(p0 + lp)*H + hh + c*8] = *(const short8*)&sT[lp*136 + hh + c*8];
    }
    if (tid < H) { atomicAdd(&gS[tid], sS[tid]); atomicAdd(&gSS[tid], sSS[tid]); }
}

// ---- BN stats -> scale/shift ----
__global__ void k_stats(const float* __restrict__ S, const float* __restrict__ SS,
                        const float* __restrict__ g, const float* __restrict__ b,
                        float invCount, float* __restrict__ scale, float* __restrict__ shift) {
    int j = threadIdx.x;
    float mu = S[j]*invCount;
    float var = SS[j]*invCount - mu*mu;
    float sc = rsqrtf(var + BN_EPS)*g[j];
    scale[j] = sc;
    shift[j] = b[j] - mu*sc;
}

// ---- fused: msg = relu( relu(bn(h1)) @ W2m + b2m ) -> in-block segment-reduce -> agg (f32) ----
// One block = 128 CSR-sorted positions; h1 reads are contiguous.
__launch_bounds__(256)
__global__ void k_fused2(const unsigned short* __restrict__ hb,
                         const float* __restrict__ scale, const float* __restrict__ shift,
                         const unsigned short* __restrict__ W2mT, const float* __restrict__ b2m,
                         const int* __restrict__ ei, const int* __restrict__ elist,
                         const int* __restrict__ offsets, float* __restrict__ agg) {
    __shared__ short sA[128*136];      // BN+ReLU(h1) tile, then msg tile
    __shared__ int rows[128];
    const int tid = threadIdx.x;
    const int p0 = blockIdx.x*128;
    if (tid < 128) rows[tid] = ei[elist[p0 + tid]];
    {
        const int rowl = tid >> 1, half = (tid & 1)*64;
        const size_t base = ((size_t)p0 + rowl)*H + half;
        #pragma unroll
        for (int c = 0; c < 8; ++c) {
            int k0 = half + c*8;
            short8 raw = *(const short8*)&hb[base + c*8];
            float4 sc0 = *(const float4*)&scale[k0], sc1 = *(const float4*)&scale[k0 + 4];
            float4 sh0 = *(const float4*)&shift[k0], sh1 = *(const float4*)&shift[k0 + 4];
            short8 o;
            o[0] = (short)f2bf(fmaxf(fmaf(bf2f((unsigned short)raw[0]), sc0.x, sh0.x), 0.f));
            o[1] = (short)f2bf(fmaxf(fmaf(bf2f((unsigned short)raw[1]), sc0.y, sh0.y), 0.f));
            o[2] = (short)f2bf(fmaxf(fmaf(bf2f((unsigned short)raw[2]), sc0.z, sh0.z), 0.f));
            o[3] = (short)f2bf(fmaxf(fmaf(bf2f((unsigned short)raw[3]), sc0.w, sh0.w), 0.f));
            o[4] = (short)f2bf(fmaxf(fmaf(bf2f((unsigned short)raw[4]), sc1.x, sh1.x), 0.f));
            o[5] = (short)f2bf(fmaxf(fmaf(bf2f((unsigned short)raw[5]), sc1.y, sh1.y), 0.f));
            o[6] = (short)f2bf(fmaxf(fmaf(bf2f((unsigned short)raw[6]), sc1.z, sh1.z), 0.f));
            o[7] = (short)f2bf(fmaxf(fmaf(bf2f((unsigned short)raw[7]), sc1.w, sh1.w), 0.f));
            *(short8*)&sA[rowl*136 + k0] = o;
        }
    }
    __syncthreads();
    const int wave = tid >> 6, lane = tid & 63;
    const int m0 = (wave & 1)*64, n0 = (wave >> 1)*64;
    f32x4 acc[4][4];
    f32x4 z = {0.f, 0.f, 0.f, 0.f};
    #pragma unroll
    for (int mt = 0; mt < 4; ++mt)
        #pragma unroll
        for (int nt = 0; nt < 4; ++nt) acc[mt][nt] = z;
    gemm_tile<4>(sA + m0*136, 136, W2mT, 128, n0, acc, lane);
    __syncthreads();   // all A-tile reads done; safe to overwrite with msg
    const int mr = lane & 15, quad = lane >> 4;
    #pragma unroll
    for (int nt = 0; nt < 4; ++nt) {
        int j = n0 + nt*16 + mr;
        float bias = b2m[j];
        #pragma unroll
        for (int mt = 0; mt < 4; ++mt) {
            int m = m0 + mt*16 + quad*4;
            #pragma unroll
            for (int r = 0; r < 4; ++r)
                sA[(m + r)*136 + j] = (short)f2bf(fmaxf(acc[mt][nt][r] + bias, 0.f));
        }
    }
    __syncthreads();
    // segment reduce by row (rows[] non-decreasing: positions are CSR-sorted)
    if (tid < 128) {
        const int jf = tid;
        int p = 0;
        while (p < 128) {
            int r = rows[p];
            int q = p + 1;
            while (q < 128 && rows[q] == r) ++q;
            float sum = 0.f;
            for (int i = p; i < q; ++i) sum += bf2f((unsigned short)sA[i*136 + jf]);
            bool full = (p0 + p == offsets[r]) && (p0 + q == offsets[r + 1]);
            float* dst = &agg[(size_t)r*H + jf];
            if (full) *dst = sum;
            else atomicAdd(dst, sum);
            p = q;
        }
    }
}

// ---- h2 = [x, agg] @ Wn1 + bn1 (f32 store) ; BN stats ----
__launch_bounds__(256)
__global__ void k_node1(const float* __restrict__ x, const float* __restrict__ agg,
                        const unsigned short* __restrict__ Wn1T, const float* __restrict__ bn1,
                        float* __restrict__ h2, float* __restrict__ gS, float* __restrict__ gSS) {
    __shared__ short sA[128*200];
    __shared__ float sS[H], sSS[H];
    const int tid = threadIdx.x;
    if (tid < H) { sS[tid] = 0.f; sSS[tid] = 0.f; }
    const int n0b = blockIdx.x*128;
    {
        const int rowl = tid >> 1, half = (tid & 1)*96;
        const int node = n0b + rowl;
        const bool ok = node < NNODES;
        #pragma unroll
        for (int c = 0; c < 12; ++c) {
            int k0 = half + c*8;
            short8 o = s8z();
            if (ok) {
                float4 a, b;
                if (k0 < 64) {
                    a = *(const float4*)&x[node*64 + k0];
                    b = *(const float4*)&x[node*64 + k0 + 4];
                } else {
                    a = *(const float4*)&agg[(size_t)node*H + (k0 - 64)];
                    b = *(const float4*)&agg[(size_t)node*H + (k0 - 64) + 4];
                }
                o[0]=(short)f2bf(a.x); o[1]=(short)f2bf(a.y); o[2]=(short)f2bf(a.z); o[3]=(short)f2bf(a.w);
                o[4]=(short)f2bf(b.x); o[5]=(short)f2bf(b.y); o[6]=(short)f2bf(b.z); o[7]=(short)f2bf(b.w);
            }
            *(short8*)&sA[rowl*200 + k0] = o;
        }
    }
    __syncthreads();
    const int wave = tid >> 6, lane = tid & 63;
    const int m0 = (wave & 1)*64, n0 = (wave >> 1)*64;
    f32x4 acc[4][4];
    f32x4 z = {0.f, 0.f, 0.f, 0.f};
    #pragma unroll
    for (int mt = 0; mt < 4; ++mt)
        #pragma unroll
        for (int nt = 0; nt < 4; ++nt) acc[mt][nt] = z;
    gemm_tile<6>(sA + m0*200, 200, Wn1T, 192, n0, acc, lane);
    const int mr = lane & 15, quad = lane >> 4;
    #pragma unroll
    for (int nt = 0; nt < 4; ++nt) {
        int j = n0 + nt*16 + mr;
        float bias = bn1[j];
        float s = 0.f, ssum = 0.f;
        #pragma unroll
        for (int mt = 0; mt < 4; ++mt) {
            int nb = n0b + m0 + mt*16 + quad*4;
            #pragma unroll
            for (int r = 0; r < 4; ++r) {
                int node = nb + r;
                if (node < NNODES) {
                    float v = acc[mt][nt][r] + bias;
                    h2[(size_t)node*H + j] = v;
                    s += v; ssum += v*v;
                }
            }
        }
        atomicAdd(&sS[j], s);
        atomicAdd(&sSS[j], ssum);
    }
    __syncthreads();
    if (tid < H) { atomicAdd(&gS[tid], sS[tid]); atomicAdd(&gSS[tid], sSS[tid]); }
}

// ---- out = relu(bn(h2)) @ Wn2 + bn2 (f32) ----
__launch_bounds__(256)
__global__ void k_node2(const float* __restrict__ h2, const float* __restrict__ scale,
                        const float* __restrict__ shift, const unsigned short* __restrict__ Wn2T,
                        const float* __restrict__ bn2, float* __restrict__ out) {
    __shared__ short sA[128*136];
    const int tid = threadIdx.x;
    const int n0b = blockIdx.x*128;
    {
        const int rowl = tid >> 1, half = (tid & 1)*64;
        const int node = n0b + rowl;
        const bool ok = node < NNODES;
        #pragma unroll
        for (int c = 0; c < 8; ++c) {
            int k0 = half + c*8;
            short8 o = s8z();
            if (ok) {
                float4 a = *(const float4*)&h2[(size_t)node*H + k0];
                float4 b = *(const float4*)&h2[(size_t)node*H + k0 + 4];
                float4 sc0 = *(const float4*)&scale[k0], sc1 = *(const float4*)&scale[k0 + 4];
                float4 sh0 = *(const float4*)&shift[k0], sh1 = *(const float4*)&shift[k0 + 4];
                o[0] = (short)f2bf(fmaxf(fmaf(a.x, sc0.x, sh0.x), 0.f));
                o[1] = (short)f2bf(fmaxf(fmaf(a.y, sc0.y, sh0.y), 0.f));
                o[2] = (short)f2bf(fmaxf(fmaf(a.z, sc0.z, sh0.z), 0.f));
                o[3] = (short)f2bf(fmaxf(fmaf(a.w, sc0.w, sh0.w), 0.f));
                o[4] = (short)f2bf(fmaxf(fmaf(b.x, sc1.x, sh1.x), 0.f));
                o[5] = (short)f2bf(fmaxf(fmaf(b.y, sc1.y, sh1.y), 0.f));
                o[6] = (short)f2bf(fmaxf(fmaf(b.z, sc1.z, sh1.z), 0.f));
                o[7] = (short)f2bf(fmaxf(fmaf(b.w, sc1.w, sh1.w), 0.f));
            }
            *(short8*)&sA[rowl*136 + k0] = o;
        }
    }
    __syncthreads();
    const int wave = tid >> 6, lane = tid & 63;
    const int m0 = (wave & 1)*64, n0 = (wave >> 1)*64;
    f32x4 acc[4][4];
    f32x4 z = {0.f, 0.f, 0.f, 0.f};
    #pragma unroll
    for (int mt = 0; mt < 4; ++mt)
        #pragma unroll
        for (int nt = 0; nt < 4; ++nt) acc[mt][nt] = z;
    gemm_tile<4>(sA + m0*136, 136, Wn2T, 128, n0, acc, lane);
    const int mr = lane & 15, quad = lane >> 4;
    #pragma unroll
    for (int nt = 0; nt < 4; ++nt) {
        int j = n0 + nt*16 + mr;
        float bias = bn2[j];
        #pragma unroll
        for (int mt = 0; mt < 4; ++mt) {
            int nb = n0b + m0 + mt*16 + quad*4;
            #pragma unroll
            for (int r = 0; r < 4; ++r) {
                int node = nb + r;
                if (node < NNODES) out[(size_t)node*H + j] = acc[mt][nt][r] + bias;
            }
        }
    }
}

extern "C" void kernel_launch(void* const* d_in, const int* in_sizes, int n_in,
                              void* d_out, int out_size, void* d_ws, size_t ws_size,
                              hipStream_t stream) {
    (void)in_sizes; (void)n_in; (void)out_size; (void)ws_size;
    const float* x   = (const float*)d_in[0];
    const int*   ei  = (const int*)d_in[1];
    const float* ea  = (const float*)d_in[2];
    const float* We1 = (const float*)d_in[3];
    const float* be1 = (const float*)d_in[4];
    const float* ge  = (const float*)d_in[5];
    const float* bbe = (const float*)d_in[6];
    const float* We2 = (const float*)d_in[7];
    const float* be2 = (const float*)d_in[8];
    const float* Wm  = (const float*)d_in[9];
    const float* bm  = (const float*)d_in[10];
    const float* Wn1 = (const float*)d_in[11];
    const float* bn1 = (const float*)d_in[12];
    const float* gn  = (const float*)d_in[13];
    const float* bbn = (const float*)d_in[14];
    const float* Wn2 = (const float*)d_in[15];
    const float* bn2 = (const float*)d_in[16];
    float* out = (float*)d_out;

    char* ws = (char*)d_ws;
    // [0, 204.8M)          h1 bf16 [E][128], SORTED order (dead after k_fused2)
    // [204.8M, 230.4M)     CSR (dead after k_fused2), then h2 f32 [N][128] overlays (k_node1)
    // [230.4M, 256M)       T bf16 [N][256] (dead after k_gather2), then agg f32 [N][128] overlays
    // [256M, ~256.23M)     stats + folded weights + transposed bf16 weights
    unsigned short* hb   = (unsigned short*)(ws);
    float*          h2   = (float*)(ws + 204800000);
    int* cnt     = (int*)(ws + 204800000);
    int* offsets = (int*)(ws + 205000192);
    int* cursor  = (int*)(ws + 205200256);
    int* elist   = (int*)(ws + 205400320);       // 3.2MB -> ends 208,600,320 (< 230.4M)
    unsigned short* Tbuf = (unsigned short*)(ws + 230400000);
    float*          agg  = (float*)(ws + 230400000);
    float* S1     = (float*)(ws + 256000000);
    float* SS1    = S1 + 128;
    float* S2     = S1 + 256;
    float* SS2    = S1 + 384;
    float* scale1 = S1 + 512;
    float* shift1 = S1 + 640;
    float* scale2 = S1 + 768;
    float* shift2 = S1 + 896;
    float* W2m = (float*)(ws + 256004096);
    float* b2m = (float*)(ws + 256069632);
    unsigned short* WabT = (unsigned short*)(ws + 256070144);
    unsigned short* Wn1T = (unsigned short*)(ws + 256102912);
    unsigned short* Wn2T = (unsigned short*)(ws + 256152064);
    unsigned short* W2mT = (unsigned short*)(ws + 256184832);
    unsigned short* WcT  = (unsigned short*)(ws + 256217600);

    hipMemsetAsync(cnt, 0, NNODES*sizeof(int), stream);
    hipMemsetAsync(S1, 0, 512*sizeof(float), stream);

    k_fold<<<H + 1, H, 0, stream>>>(We2, be2, Wm, bm, W2m, b2m);
    k_prep2<<<304, 256, 0, stream>>>(We1, Wn1, Wn2, W2m, WabT, Wn1T, Wn2T, W2mT, WcT);
    k_count<<<NEDGES/256, 256, 0, stream>>>(ei, cnt);
    k_scan<<<1, 1024, 0, stream>>>(cnt, offsets, cursor);
    k_scatter<<<NEDGES/256, 256, 0, stream>>>(ei, cursor, elist);
    k_T<<<dim3(391, 2), 256, 0, stream>>>(x, WabT, Tbuf);
    k_gather2<<<NEDGES/128, 256, 0, stream>>>(Tbuf, ei, elist, ea, WcT, be1, hb, S1, SS1);
    k_stats<<<1, H, 0, stream>>>(S1, SS1, ge, bbe, 1.0f/NEDGES, scale1, shift1);
    // T is dead now; zero agg (overlays T) before the fused scatter-reduce
    hipMemsetAsync(agg, 0, (size_t)NNODES*H*sizeof(float), stream);
    k_fused2<<<NEDGES/128, 256, 0, stream>>>(hb, scale1, shift1, W2mT, b2m,
                                             ei, elist, offsets, agg);
    k_node1<<<391, 256, 0, stream>>>(x, agg, Wn1T, bn1, h2, S2, SS2);
    k_stats<<<1, H, 0, stream>>>(S2, SS2, gn, bbn, 1.0f/NNODES, scale2, shift2);
    k_node2<<<391, 256, 0, stream>>>(h2, scale2, shift2, Wn2T, bn2, out);
}

// Round 7
// 697.350 us; speedup vs baseline: 1.0823x; 1.0823x over previous
//
#include <hip/hip_runtime.h>
#include <stdint.h>

#define NNODES 50000
#define NEDGES 800000
#define H 128
#define BN_EPS 1e-5f

typedef short short8 __attribute__((ext_vector_type(8)));
typedef float f32x4 __attribute__((ext_vector_type(4)));

__device__ __forceinline__ float bf2f(unsigned short u) {
    unsigned int v = ((unsigned int)u) << 16;
    return __uint_as_float(v);
}
__device__ __forceinline__ unsigned short f2bf(float f) {
    unsigned int x = __float_as_uint(f);
    return (unsigned short)((x + 0x7FFFu + ((x >> 16) & 1u)) >> 16);
}
__device__ __forceinline__ short8 s8z() { short8 z = {0,0,0,0,0,0,0,0}; return z; }

// ================= common MFMA tile core (k_T / k_node1 / k_node2) =================
template<int KB>
__device__ __forceinline__ void gemm_tile(const short* __restrict__ sA, const int SK,
                                          const unsigned short* __restrict__ WT, const int RK,
                                          const int n0, f32x4 acc[4][4], const int lane) {
    const int mr = lane & 15, quad = lane >> 4;
    const short* W = (const short*)WT;
    #pragma unroll
    for (int kb = 0; kb < KB; ++kb) {
        short8 a[4];
        #pragma unroll
        for (int mt = 0; mt < 4; ++mt)
            a[mt] = *(const short8*)&sA[(mt*16 + mr)*SK + kb*32 + quad*8];
        #pragma unroll
        for (int nt = 0; nt < 4; ++nt) {
            short8 b = *(const short8*)&W[(size_t)(n0 + nt*16 + mr)*RK + kb*32 + quad*8];
            #pragma unroll
            for (int mt = 0; mt < 4; ++mt)
                acc[mt][nt] = __builtin_amdgcn_mfma_f32_16x16x32_bf16(a[mt], b, acc[mt][nt], 0, 0, 0);
        }
    }
}

// ---- fold We2@Wm -> W2m (f32), b2m = be2@Wm + bm ----
__global__ void k_fold(const float* __restrict__ We2, const float* __restrict__ be2,
                       const float* __restrict__ Wm, const float* __restrict__ bm,
                       float* __restrict__ W2m, float* __restrict__ b2m) {
    int j = threadIdx.x;
    int i = blockIdx.x;
    if (i < H) {
        float acc = 0.f;
        for (int k = 0; k < H; ++k) acc = fmaf(We2[i*H + k], Wm[k*H + j], acc);
        W2m[i*H + j] = acc;
    } else {
        float acc = bm[j];
        for (int k = 0; k < H; ++k) acc = fmaf(be2[k], Wm[k*H + j], acc);
        b2m[j] = acc;
    }
}

// ---- transposed bf16 weights + zero-init of cnt and BN-stat accumulators ----
__global__ void k_prep2(const float* __restrict__ We1, const float* __restrict__ Wn1,
                        const float* __restrict__ Wn2,
                        unsigned short* __restrict__ WabT, unsigned short* __restrict__ Wn1T,
                        unsigned short* __restrict__ Wn2T, unsigned short* __restrict__ WcT,
                        int* __restrict__ cnt, float* __restrict__ S1f) {
    int i = blockIdx.x*256 + threadIdx.x;
    if (i < 16384) {                        // WabT[256][64]
        int n = i >> 6, k = i & 63;
        WabT[n*64 + k] = f2bf(We1[(n < 128 ? k : 64 + k)*H + (n & 127)]);
    } else if (i < 40960) {                 // Wn1T[128][192]
        int j = i - 16384; int n = j / 192, k = j - n*192;
        Wn1T[n*192 + k] = f2bf(Wn1[k*H + n]);
    } else if (i < 57344) {                 // Wn2T[128][128]
        int j = i - 40960; int n = j >> 7, k = j & 127;
        Wn2T[n*H + k] = f2bf(Wn2[k*H + n]);
    } else if (i < 61440) {                 // WcT[128][32], k>=16 zero
        int j = i - 57344; int n = j >> 5, k = j & 31;
        WcT[n*32 + k] = (k < 16) ? f2bf(We1[(128 + k)*H + n]) : (unsigned short)0;
    } else if (i < 111440) {
        cnt[i - 61440] = 0;
    } else if (i < 112464) {
        S1f[i - 111440] = 0.f;
    }
}

// ---- CSR build ----
__global__ void k_count(const int* __restrict__ ei, int* __restrict__ cnt) {
    int e = blockIdx.x*256 + threadIdx.x;
    if (e < NEDGES) atomicAdd(&cnt[ei[e]], 1);
}

// multi-block scan: A = per-block sums, B = scan of block sums, C = final offsets
__global__ void k_scanA(const int* __restrict__ cnt, int* __restrict__ bsum) {
    __shared__ int ws[4];
    const int tid = threadIdx.x;
    int i = blockIdx.x*256 + tid;
    int v = (i < NNODES) ? cnt[i] : 0;
    #pragma unroll
    for (int off = 32; off > 0; off >>= 1) v += __shfl_down(v, off);
    if ((tid & 63) == 0) ws[tid >> 6] = v;
    __syncthreads();
    if (tid == 0) bsum[blockIdx.x] = ws[0] + ws[1] + ws[2] + ws[3];
}

__global__ void k_scanB(const int* __restrict__ bsum, int* __restrict__ bpre,
                        int* __restrict__ offsets) {
    __shared__ int ws[4];
    const int tid = threadIdx.x;
    const int lane = tid & 63, wid = tid >> 6;
    int v = (tid < 196) ? bsum[tid] : 0;
    int xv = v;
    #pragma unroll
    for (int off = 1; off < 64; off <<= 1) {
        int y = __shfl_up(xv, off);
        if (lane >= off) xv += y;
    }
    if (lane == 63) ws[wid] = xv;
    __syncthreads();
    int base = 0;
    for (int w = 0; w < 4; ++w) if (w < wid) base += ws[w];
    int incl = base + xv;
    if (tid < 196) bpre[tid] = incl - v;
    if (tid == 255) offsets[NNODES] = incl;
}

__global__ void k_scanC(const int* __restrict__ cnt, const int* __restrict__ bpre,
                        int* __restrict__ offsets, int* __restrict__ cursor) {
    __shared__ int ws[4];
    const int tid = threadIdx.x;
    const int lane = tid & 63, wid = tid >> 6;
    int i = blockIdx.x*256 + tid;
    int v = (i < NNODES) ? cnt[i] : 0;
    int xv = v;
    #pragma unroll
    for (int off = 1; off < 64; off <<= 1) {
        int y = __shfl_up(xv, off);
        if (lane >= off) xv += y;
    }
    if (lane == 63) ws[wid] = xv;
    __syncthreads();
    int base = bpre[blockIdx.x];
    for (int w = 0; w < 4; ++w) if (w < wid) base += ws[w];
    int excl = base + xv - v;
    if (i < NNODES) { offsets[i] = excl; cursor[i] = excl; }
}

__global__ void k_scatter(const int* __restrict__ ei, int* __restrict__ cursor,
                          int* __restrict__ elist) {
    int e = blockIdx.x*256 + threadIdx.x;
    if (e < NEDGES) {
        int p = atomicAdd(&cursor[ei[e]], 1);
        elist[p] = e;
    }
}

// ---- T = x @ [Wa | Wb]  (bf16 out, [50000][256]) ----
__launch_bounds__(256)
__global__ void k_T(const float* __restrict__ x, const unsigned short* __restrict__ WabT,
                    unsigned short* __restrict__ T) {
    __shared__ short sA[128*72];
    const int tid = threadIdx.x;
    const int n0b = blockIdx.x*128;
    {
        const int rowl = tid >> 1, half = (tid & 1)*32;
        const int node = n0b + rowl;
        const bool ok = node < NNODES;
        #pragma unroll
        for (int c = 0; c < 4; ++c) {
            int k0 = half + c*8;
            short8 o = s8z();
            if (ok) {
                float4 a = *(const float4*)&x[node*64 + k0];
                float4 b = *(const float4*)&x[node*64 + k0 + 4];
                o[0]=(short)f2bf(a.x); o[1]=(short)f2bf(a.y); o[2]=(short)f2bf(a.z); o[3]=(short)f2bf(a.w);
                o[4]=(short)f2bf(b.x); o[5]=(short)f2bf(b.y); o[6]=(short)f2bf(b.z); o[7]=(short)f2bf(b.w);
            }
            *(short8*)&sA[rowl*72 + k0] = o;
        }
    }
    __syncthreads();
    const int wave = tid >> 6, lane = tid & 63;
    const int m0 = (wave & 1)*64;
    const int n0 = blockIdx.y*128 + (wave >> 1)*64;
    f32x4 acc[4][4];
    f32x4 z = {0.f, 0.f, 0.f, 0.f};
    #pragma unroll
    for (int mt = 0; mt < 4; ++mt)
        #pragma unroll
        for (int nt = 0; nt < 4; ++nt) acc[mt][nt] = z;
    gemm_tile<2>(sA + m0*72, 72, WabT, 64, n0, acc, lane);
    const int mr = lane & 15, quad = lane >> 4;
    #pragma unroll
    for (int nt = 0; nt < 4; ++nt) {
        int j = n0 + nt*16 + mr;
        #pragma unroll
        for (int mt = 0; mt < 4; ++mt) {
            int nb = n0b + m0 + mt*16 + quad*4;
            #pragma unroll
            for (int r = 0; r < 4; ++r) {
                int node = nb + r;
                if (node < NNODES) T[(size_t)node*256 + j] = f2bf(acc[mt][nt][r]);
            }
        }
    }
}

// ---- h1[p] (sorted order, FRAGMENT layout) = T1[row]+T2[col]+ea@Wc+be1 ; BN stats ----
// Wave w: rows w*32..w*32+31, full 128 cols. A (ea) loaded straight to registers.
__launch_bounds__(256)
__global__ void k_gather3(const unsigned short* __restrict__ T, const int* __restrict__ ei,
                          const int* __restrict__ elist, const float* __restrict__ ea,
                          const unsigned short* __restrict__ WcT, const float* __restrict__ be1,
                          unsigned short* __restrict__ hb,
                          float* __restrict__ gS, float* __restrict__ gSS) {
    __shared__ short sT[128*136];      // bf16(T1+T2), then finished h1 tile
    __shared__ float sS[H], sSS[H];
    __shared__ int sE[128];
    const int tid = threadIdx.x;
    const int p0 = blockIdx.x*128;
    if (tid < 128) { sS[tid] = 0.f; sSS[tid] = 0.f; sE[tid] = elist[p0 + tid]; }
    __syncthreads();                   // B1: sE visible
    const int lp = tid >> 1, half = tid & 1;
    {
        const int e = sE[lp];
        const int row = ei[e], col = ei[NEDGES + e];
        #pragma unroll
        for (int c = 0; c < 8; ++c) {
            int jj = half*64 + c*8;
            short8 t1 = *(const short8*)&T[(size_t)row*256 + jj];
            short8 t2 = *(const short8*)&T[(size_t)col*256 + 128 + jj];
            short8 o;
            #pragma unroll
            for (int i = 0; i < 8; ++i)
                o[i] = (short)f2bf(bf2f((unsigned short)t1[i]) + bf2f((unsigned short)t2[i]));
            *(short8*)&sT[lp*136 + jj] = o;
        }
    }
    const int wave = tid >> 6, lane = tid & 63;
    const int mr = lane & 15, quad = lane >> 4;
    const int mbase = wave*32;
    short8 a0 = s8z(), a1 = s8z();
    if (quad < 2) {
        const float4* ea4 = (const float4*)ea;
        int e0i = sE[mbase + mr];
        int e1i = sE[mbase + 16 + mr];
        float4 u = ea4[(size_t)e0i*4 + quad*2];
        float4 v = ea4[(size_t)e0i*4 + quad*2 + 1];
        a0[0]=(short)f2bf(u.x); a0[1]=(short)f2bf(u.y); a0[2]=(short)f2bf(u.z); a0[3]=(short)f2bf(u.w);
        a0[4]=(short)f2bf(v.x); a0[5]=(short)f2bf(v.y); a0[6]=(short)f2bf(v.z); a0[7]=(short)f2bf(v.w);
        u = ea4[(size_t)e1i*4 + quad*2];
        v = ea4[(size_t)e1i*4 + quad*2 + 1];
        a1[0]=(short)f2bf(u.x); a1[1]=(short)f2bf(u.y); a1[2]=(short)f2bf(u.z); a1[3]=(short)f2bf(u.w);
        a1[4]=(short)f2bf(v.x); a1[5]=(short)f2bf(v.y); a1[6]=(short)f2bf(v.z); a1[7]=(short)f2bf(v.w);
    }
    f32x4 acc[2][8];
    f32x4 z = {0.f, 0.f, 0.f, 0.f};
    #pragma unroll
    for (int mt = 0; mt < 2; ++mt)
        #pragma unroll
        for (int nt = 0; nt < 8; ++nt) acc[mt][nt] = z;
    #pragma unroll
    for (int nt = 0; nt < 8; ++nt) {
        short8 b = *(const short8*)&WcT[(nt*16 + mr)*32 + quad*8];
        acc[0][nt] = __builtin_amdgcn_mfma_f32_16x16x32_bf16(a0, b, acc[0][nt], 0, 0, 0);
        acc[1][nt] = __builtin_amdgcn_mfma_f32_16x16x32_bf16(a1, b, acc[1][nt], 0, 0, 0);
    }
    __syncthreads();                   // B2: sT staging complete
    #pragma unroll
    for (int nt = 0; nt < 8; ++nt) {
        int j = nt*16 + mr;
        float bia = be1[j];
        float s = 0.f, ssum = 0.f;
        #pragma unroll
        for (int mt = 0; mt < 2; ++mt) {
            #pragma unroll
            for (int r = 0; r < 4; ++r) {
                int m = mbase + mt*16 + quad*4 + r;
                float v = acc[mt][nt][r] + bf2f((unsigned short)sT[m*136 + j]) + bia;
                sT[m*136 + j] = (short)f2bf(v);
                s += v; ssum += v*v;
            }
        }
        atomicAdd(&sS[j], s);
        atomicAdd(&sSS[j], ssum);
    }
    __syncthreads();                   // B3: h1 tile finished
    // fragment-layout coalesced store: chunk (kb,quadS) plane, contiguous in row lp
    #pragma unroll
    for (int c = 0; c < 8; ++c) {
        int k0 = half*64 + c*8;
        int kb = k0 >> 5, quadS = (k0 >> 3) & 3;
        *(short8*)&hb[((size_t)(blockIdx.x*16 + kb*4 + quadS)*128 + lp)*8] =
            *(const short8*)&sT[lp*136 + k0];
    }
    if (tid < 128) { atomicAdd(&gS[tid], sS[tid]); atomicAdd(&gSS[tid], sSS[tid]); }
}

// ---- BN stats -> scale/shift ----
__global__ void k_stats(const float* __restrict__ S, const float* __restrict__ SS,
                        const float* __restrict__ g, const float* __restrict__ b,
                        float invCount, float* __restrict__ scale, float* __restrict__ shift) {
    int j = threadIdx.x;
    float mu = S[j]*invCount;
    float var = SS[j]*invCount - mu*mu;
    float sc = rsqrtf(var + BN_EPS)*g[j];
    scale[j] = sc;
    shift[j] = b[j] - mu*sc;
}

// ---- post-stats fold: W2mST[n][k] = bf16(sc[k]*W2m[k][n]); t = sh/sc; zero agg ----
__global__ void k_prep3(const float* __restrict__ W2m, const float* __restrict__ scale,
                        const float* __restrict__ shift, unsigned short* __restrict__ W2mST,
                        float* __restrict__ tvec, float* __restrict__ agg) {
    int i = blockIdx.x*256 + threadIdx.x;
    if (i < 16384) {
        int n = i >> 7, k = i & 127;
        W2mST[n*H + k] = f2bf(scale[k] * W2m[k*H + n]);
    } else if (i < 16512) {
        int k = i - 16384;
        tvec[k] = shift[k] / scale[k];
    } else if (i < 16512 + NNODES*H) {
        agg[i - 16512] = 0.f;
    }
}

// ---- fused: msg = relu( relu(h1+t) @ W2mS + b2m ) -> parallel segment-reduce -> agg ----
// A-frags straight from fragment-layout h1 (no LDS staging); one block = 128 sorted edges.
__launch_bounds__(256)
__global__ void k_msgagg(const unsigned short* __restrict__ hb, const float* __restrict__ tvec,
                         const unsigned short* __restrict__ W2mST, const float* __restrict__ b2m,
                         const int* __restrict__ ei, const int* __restrict__ elist,
                         const int* __restrict__ offsets, float* __restrict__ agg) {
    __shared__ short sA[128*136];      // msg tile
    __shared__ int rows[128];
    __shared__ int segStart[130];
    __shared__ int wcnt[2];
    __shared__ int nsegS;
    const int tid = threadIdx.x;
    const int p0 = blockIdx.x*128;
    int pre = 0, st = 0;
    if (tid < 128) rows[tid] = ei[elist[p0 + tid]];
    __syncthreads();                   // B1
    if (tid < 128) {
        int r0 = rows[tid];
        st = (tid == 0) || (rows[tid - 1] != r0);
        unsigned long long m = __ballot(st);
        int lane = tid & 63;
        pre = __popcll(m & ((1ull << lane) - 1ull));
        if (lane == 63) wcnt[tid >> 6] = pre + st;
    }
    __syncthreads();                   // B2
    if (tid < 128) {
        int base = (tid >= 64) ? wcnt[0] : 0;
        int sid = base + pre + st - 1;
        if (st) segStart[sid] = tid;
        if (tid == 127) {
            int ns = wcnt[0] + wcnt[1];
            nsegS = ns;
            segStart[ns] = 128;
        }
    }
    // barrier-free GEMM: A from global fragment layout, B from L2-hot W2mST
    const int wave = tid >> 6, lane = tid & 63;
    const int mr = lane & 15, quad = lane >> 4;
    const int mbase = wave*32;
    f32x4 acc[2][8];
    f32x4 z = {0.f, 0.f, 0.f, 0.f};
    #pragma unroll
    for (int mt = 0; mt < 2; ++mt)
        #pragma unroll
        for (int nt = 0; nt < 8; ++nt) acc[mt][nt] = z;
    #pragma unroll
    for (int kb = 0; kb < 4; ++kb) {
        float4 tq0 = *(const float4*)&tvec[kb*32 + quad*8];
        float4 tq1 = *(const float4*)&tvec[kb*32 + quad*8 + 4];
        short8 a[2];
        #pragma unroll
        for (int mt = 0; mt < 2; ++mt) {
            short8 raw = *(const short8*)&hb[((size_t)(blockIdx.x*16 + kb*4 + quad)*128
                                             + mbase + mt*16 + mr)*8];
            short8 av;
            av[0] = (short)f2bf(fmaxf(bf2f((unsigned short)raw[0]) + tq0.x, 0.f));
            av[1] = (short)f2bf(fmaxf(bf2f((unsigned short)raw[1]) + tq0.y, 0.f));
            av[2] = (short)f2bf(fmaxf(bf2f((unsigned short)raw[2]) + tq0.z, 0.f));
            av[3] = (short)f2bf(fmaxf(bf2f((unsigned short)raw[3]) + tq0.w, 0.f));
            av[4] = (short)f2bf(fmaxf(bf2f((unsigned short)raw[4]) + tq1.x, 0.f));
            av[5] = (short)f2bf(fmaxf(bf2f((unsigned short)raw[5]) + tq1.y, 0.f));
            av[6] = (short)f2bf(fmaxf(bf2f((unsigned short)raw[6]) + tq1.z, 0.f));
            av[7] = (short)f2bf(fmaxf(bf2f((unsigned short)raw[7]) + tq1.w, 0.f));
            a[mt] = av;
        }
        #pragma unroll
        for (int nt = 0; nt < 8; ++nt) {
            short8 b = *(const short8*)&W2mST[(nt*16 + mr)*H + kb*32 + quad*8];
            acc[0][nt] = __builtin_amdgcn_mfma_f32_16x16x32_bf16(a[0], b, acc[0][nt], 0, 0, 0);
            acc[1][nt] = __builtin_amdgcn_mfma_f32_16x16x32_bf16(a[1], b, acc[1][nt], 0, 0, 0);
        }
    }
    // msg -> LDS
    #pragma unroll
    for (int nt = 0; nt < 8; ++nt) {
        int j = nt*16 + mr;
        float bias = b2m[j];
        #pragma unroll
        for (int mt = 0; mt < 2; ++mt) {
            #pragma unroll
            for (int r = 0; r < 4; ++r) {
                int m = mbase + mt*16 + quad*4 + r;
                sA[m*136 + j] = (short)f2bf(fmaxf(acc[mt][nt][r] + bias, 0.f));
            }
        }
    }
    __syncthreads();                   // B3
    // parallel segment reduce: (seg, col) pairs over all 256 threads
    const int nseg = nsegS;
    for (int idx = tid; idx < (nseg << 7); idx += 256) {
        int s = idx >> 7, j = idx & 127;
        int a0 = segStart[s], b0 = segStart[s + 1];
        float sum = 0.f;
        for (int i = a0; i < b0; ++i) sum += bf2f((unsigned short)sA[i*136 + j]);
        int r = rows[a0];
        bool interior = (a0 > 0) && (b0 < 128);
        bool full = interior || ((p0 + a0 == offsets[r]) && (p0 + b0 == offsets[r + 1]));
        float* dst = &agg[(size_t)r*H + j];
        if (full) *dst = sum;
        else atomicAdd(dst, sum);
    }
}

// ---- h2 = [x, agg] @ Wn1 + bn1 (f32 store) ; BN stats ----
__launch_bounds__(256)
__global__ void k_node1(const float* __restrict__ x, const float* __restrict__ agg,
                        const unsigned short* __restrict__ Wn1T, const float* __restrict__ bn1,
                        float* __restrict__ h2, float* __restrict__ gS, float* __restrict__ gSS) {
    __shared__ short sA[128*200];
    __shared__ float sS[H], sSS[H];
    const int tid = threadIdx.x;
    if (tid < H) { sS[tid] = 0.f; sSS[tid] = 0.f; }
    const int n0b = blockIdx.x*128;
    {
        const int rowl = tid >> 1, half = (tid & 1)*96;
        const int node = n0b + rowl;
        const bool ok = node < NNODES;
        #pragma unroll
        for (int c = 0; c < 12; ++c) {
            int k0 = half + c*8;
            short8 o = s8z();
            if (ok) {
                float4 a, b;
                if (k0 < 64) {
                    a = *(const float4*)&x[node*64 + k0];
                    b = *(const float4*)&x[node*64 + k0 + 4];
                } else {
                    a = *(const float4*)&agg[(size_t)node*H + (k0 - 64)];
                    b = *(const float4*)&agg[(size_t)node*H + (k0 - 64) + 4];
                }
                o[0]=(short)f2bf(a.x); o[1]=(short)f2bf(a.y); o[2]=(short)f2bf(a.z); o[3]=(short)f2bf(a.w);
                o[4]=(short)f2bf(b.x); o[5]=(short)f2bf(b.y); o[6]=(short)f2bf(b.z); o[7]=(short)f2bf(b.w);
            }
            *(short8*)&sA[rowl*200 + k0] = o;
        }
    }
    __syncthreads();
    const int wave = tid >> 6, lane = tid & 63;
    const int m0 = (wave & 1)*64, n0 = (wave >> 1)*64;
    f32x4 acc[4][4];
    f32x4 z = {0.f, 0.f, 0.f, 0.f};
    #pragma unroll
    for (int mt = 0; mt < 4; ++mt)
        #pragma unroll
        for (int nt = 0; nt < 4; ++nt) acc[mt][nt] = z;
    gemm_tile<6>(sA + m0*200, 200, Wn1T, 192, n0, acc, lane);
    const int mr = lane & 15, quad = lane >> 4;
    #pragma unroll
    for (int nt = 0; nt < 4; ++nt) {
        int j = n0 + nt*16 + mr;
        float bias = bn1[j];
        float s = 0.f, ssum = 0.f;
        #pragma unroll
        for (int mt = 0; mt < 4; ++mt) {
            int nb = n0b + m0 + mt*16 + quad*4;
            #pragma unroll
            for (int r = 0; r < 4; ++r) {
                int node = nb + r;
                if (node < NNODES) {
                    float v = acc[mt][nt][r] + bias;
                    h2[(size_t)node*H + j] = v;
                    s += v; ssum += v*v;
                }
            }
        }
        atomicAdd(&sS[j], s);
        atomicAdd(&sSS[j], ssum);
    }
    __syncthreads();
    if (tid < H) { atomicAdd(&gS[tid], sS[tid]); atomicAdd(&gSS[tid], sSS[tid]); }
}

// ---- out = relu(bn(h2)) @ Wn2 + bn2 (f32) ----
__launch_bounds__(256)
__global__ void k_node2(const float* __restrict__ h2, const float* __restrict__ scale,
                        const float* __restrict__ shift, const unsigned short* __restrict__ Wn2T,
                        const float* __restrict__ bn2, float* __restrict__ out) {
    __shared__ short sA[128*136];
    const int tid = threadIdx.x;
    const int n0b = blockIdx.x*128;
    {
        const int rowl = tid >> 1, half = (tid & 1)*64;
        const int node = n0b + rowl;
        const bool ok = node < NNODES;
        #pragma unroll
        for (int c = 0; c < 8; ++c) {
            int k0 = half + c*8;
            short8 o = s8z();
            if (ok) {
                float4 a = *(const float4*)&h2[(size_t)node*H + k0];
                float4 b = *(const float4*)&h2[(size_t)node*H + k0 + 4];
                float4 sc0 = *(const float4*)&scale[k0], sc1 = *(const float4*)&scale[k0 + 4];
                float4 sh0 = *(const float4*)&shift[k0], sh1 = *(const float4*)&shift[k0 + 4];
                o[0] = (short)f2bf(fmaxf(fmaf(a.x, sc0.x, sh0.x), 0.f));
                o[1] = (short)f2bf(fmaxf(fmaf(a.y, sc0.y, sh0.y), 0.f));
                o[2] = (short)f2bf(fmaxf(fmaf(a.z, sc0.z, sh0.z), 0.f));
                o[3] = (short)f2bf(fmaxf(fmaf(a.w, sc0.w, sh0.w), 0.f));
                o[4] = (short)f2bf(fmaxf(fmaf(b.x, sc1.x, sh1.x), 0.f));
                o[5] = (short)f2bf(fmaxf(fmaf(b.y, sc1.y, sh1.y), 0.f));
                o[6] = (short)f2bf(fmaxf(fmaf(b.z, sc1.z, sh1.z), 0.f));
                o[7] = (short)f2bf(fmaxf(fmaf(b.w, sc1.w, sh1.w), 0.f));
            }
            *(short8*)&sA[rowl*136 + k0] = o;
        }
    }
    __syncthreads();
    const int wave = tid >> 6, lane = tid & 63;
    const int m0 = (wave & 1)*64, n0 = (wave >> 1)*64;
    f32x4 acc[4][4];
    f32x4 z = {0.f, 0.f, 0.f, 0.f};
    #pragma unroll
    for (int mt = 0; mt < 4; ++mt)
        #pragma unroll
        for (int nt = 0; nt < 4; ++nt) acc[mt][nt] = z;
    gemm_tile<4>(sA + m0*136, 136, Wn2T, 128, n0, acc, lane);
    const int mr = lane & 15, quad = lane >> 4;
    #pragma unroll
    for (int nt = 0; nt < 4; ++nt) {
        int j = n0 + nt*16 + mr;
        float bias = bn2[j];
        #pragma unroll
        for (int mt = 0; mt < 4; ++mt) {
            int nb = n0b + m0 + mt*16 + quad*4;
            #pragma unroll
            for (int r = 0; r < 4; ++r) {
                int node = nb + r;
                if (node < NNODES) out[(size_t)node*H + j] = acc[mt][nt][r] + bias;
            }
        }
    }
}

extern "C" void kernel_launch(void* const* d_in, const int* in_sizes, int n_in,
                              void* d_out, int out_size, void* d_ws, size_t ws_size,
                              hipStream_t stream) {
    (void)in_sizes; (void)n_in; (void)out_size; (void)ws_size;
    const float* x   = (const float*)d_in[0];
    const int*   ei  = (const int*)d_in[1];
    const float* ea  = (const float*)d_in[2];
    const float* We1 = (const float*)d_in[3];
    const float* be1 = (const float*)d_in[4];
    const float* ge  = (const float*)d_in[5];
    const float* bbe = (const float*)d_in[6];
    const float* We2 = (const float*)d_in[7];
    const float* be2 = (const float*)d_in[8];
    const float* Wm  = (const float*)d_in[9];
    const float* bm  = (const float*)d_in[10];
    const float* Wn1 = (const float*)d_in[11];
    const float* bn1 = (const float*)d_in[12];
    const float* gn  = (const float*)d_in[13];
    const float* bbn = (const float*)d_in[14];
    const float* Wn2 = (const float*)d_in[15];
    const float* bn2 = (const float*)d_in[16];
    float* out = (float*)d_out;

    char* ws = (char*)d_ws;
    // [0, 204.8M)          h1 bf16 FRAGMENT layout (dead after k_msgagg; h2 f32 overlays)
    // [204.8M, 230.4M)     agg f32 [N][128]
    // [230.4M, 256M)       T bf16 [N][256] (dead after k_gather3)
    // [256M, ~260M)        CSR + scan temps + stats + folded weights
    unsigned short* hb   = (unsigned short*)(ws);
    float*          h2   = (float*)(ws);
    float*          agg  = (float*)(ws + 204800000);
    unsigned short* Tbuf = (unsigned short*)(ws + 230400000);
    int* cnt     = (int*)(ws + 256000000);
    int* offsets = (int*)(ws + 256200192);
    int* cursor  = (int*)(ws + 256400448);
    int* bsum    = (int*)(ws + 256600448);
    int* bpre    = (int*)(ws + 256601472);
    int* elist   = (int*)(ws + 256602496);
    float* S1     = (float*)(ws + 259802496);
    float* SS1    = S1 + 128;
    float* S2     = S1 + 256;
    float* SS2    = S1 + 384;
    float* scale1 = S1 + 512;
    float* shift1 = S1 + 640;
    float* scale2 = S1 + 768;
    float* shift2 = S1 + 896;
    float* W2m  = (float*)(ws + 259806592);
    float* b2m  = (float*)(ws + 259872128);
    float* tvec = (float*)(ws + 259872640);
    unsigned short* WabT  = (unsigned short*)(ws + 259873152);
    unsigned short* Wn1T  = (unsigned short*)(ws + 259905920);
    unsigned short* Wn2T  = (unsigned short*)(ws + 259955072);
    unsigned short* W2mST = (unsigned short*)(ws + 259987840);
    unsigned short* WcT   = (unsigned short*)(ws + 260020608);

    k_fold<<<H + 1, H, 0, stream>>>(We2, be2, Wm, bm, W2m, b2m);
    k_prep2<<<440, 256, 0, stream>>>(We1, Wn1, Wn2, WabT, Wn1T, Wn2T, WcT, cnt, S1);
    k_count<<<NEDGES/256, 256, 0, stream>>>(ei, cnt);
    k_scanA<<<196, 256, 0, stream>>>(cnt, bsum);
    k_scanB<<<1, 256, 0, stream>>>(bsum, bpre, offsets);
    k_scanC<<<196, 256, 0, stream>>>(cnt, bpre, offsets, cursor);
    k_scatter<<<NEDGES/256, 256, 0, stream>>>(ei, cursor, elist);
    k_T<<<dim3(391, 2), 256, 0, stream>>>(x, WabT, Tbuf);
    k_gather3<<<NEDGES/128, 256, 0, stream>>>(Tbuf, ei, elist, ea, WcT, be1, hb, S1, SS1);
    k_stats<<<1, H, 0, stream>>>(S1, SS1, ge, bbe, 1.0f/NEDGES, scale1, shift1);
    k_prep3<<<12565, 256, 0, stream>>>(W2m, scale1, shift1, W2mST, tvec, agg);
    k_msgagg<<<NEDGES/128, 256, 0, stream>>>(hb, tvec, W2mST, b2m, ei, elist, offsets, agg);
    k_node1<<<391, 256, 0, stream>>>(x, agg, Wn1T, bn1, h2, S2, SS2);
    k_stats<<<1, H, 0, stream>>>(S2, SS2, gn, bbn, 1.0f/NNODES, scale2, shift2);
    k_node2<<<391, 256, 0, stream>>>(h2, scale2, shift2, Wn2T, bn2, out);
}